// Round 17
// baseline (255.702 us; speedup 1.0000x reference)
//
#include <hip/hip_runtime.h>
#include <hip/hip_bf16.h>

#define NB 8
#define NP 1024
#define NPTS (NB * NP)
#define KNN 20

using bf16x8 = __attribute__((ext_vector_type(8))) short;
using f32x4 = __attribute__((ext_vector_type(4))) float;
using u64x16 = __attribute__((ext_vector_type(16))) unsigned long long;
using u32x16 = __attribute__((ext_vector_type(16))) unsigned int;

static __device__ __forceinline__ unsigned long long umin64(unsigned long long a,
                                                            unsigned long long b) {
    return a < b ? a : b;
}

static __device__ __forceinline__ void split_bf16(float v, unsigned short& h,
                                                  unsigned short& l) {
    __hip_bfloat16 hb = __float2bfloat16(v);
    float hf = __bfloat162float(hb);
    __hip_bfloat16 lb = __float2bfloat16(v - hf);
    h = *(unsigned short*)&hb;
    l = *(unsigned short*)&lb;
}

// ---------------- wave-wide bitonic sorts (64 lanes, ascending) ----------
static __device__ __forceinline__ unsigned long long wave_bitonic_sort(
        unsigned long long v, int lane) {
#pragma unroll
    for (int k = 2; k <= 64; k <<= 1) {
#pragma unroll
        for (int j = k >> 1; j > 0; j >>= 1) {
            unsigned long long o = __shfl_xor(v, j, 64);
            bool tmin = (((lane & k) == 0) == ((lane & j) == 0));
            bool lt = v < o;
            v = (lt == tmin) ? v : o;
        }
    }
    return v;
}

static __device__ __forceinline__ unsigned wave_bitonic_sort_u32(unsigned v, int lane) {
#pragma unroll
    for (int k = 2; k <= 64; k <<= 1) {
#pragma unroll
        for (int j = k >> 1; j > 0; j >>= 1) {
            unsigned o = (unsigned)__shfl_xor((int)v, j, 64);
            bool tmin = (((lane & k) == 0) == ((lane & j) == 0));
            bool lt = v < o;
            v = (lt == tmin) ? v : o;
        }
    }
    return v;
}

// ---------------- wave-local top-20, exact full fallback (flat scan, u64) ----------
static __device__ __forceinline__ void topk20_wave(u64x16 k, int lane,
                                                   int* __restrict__ out) {
    for (int r = 0; r < KNN; ++r) {
        unsigned long long m = k[0];
#pragma unroll
        for (int j = 1; j < 16; ++j)
            if ((unsigned)(k[j] >> 32) < (unsigned)(m >> 32)) m = k[j];
#pragma unroll
        for (int s = 1; s < 64; s <<= 1) {
            unsigned long long o = __shfl_xor(m, s, 64);
            m = umin64(m, o);
        }
        if (lane == 0) out[r] = (int)(m & 0xffffffffu);
        if (r == KNN - 1) break;
        unsigned mlo = (unsigned)m;
#pragma unroll
        for (int j = 0; j < 16; ++j)
            if ((unsigned)k[j] == mlo) k[j] = ~0ull;
    }
}

// ---------------- wave-local top-20 SET selection (unordered output) ----------------
static __device__ __forceinline__ void topk20_sel(u32x16 d, int lane,
                                                  unsigned long long* __restrict__ cand,
                                                  int* __restrict__ out) {
    unsigned lm = d[0];
#pragma unroll
    for (int j = 1; j < 16; ++j) lm = (d[j] < lm) ? d[j] : lm;
    unsigned srt = wave_bitonic_sort_u32(lm, lane);
    unsigned T = (unsigned)__shfl((int)srt, 19, 64);  // upper bound on 20th smallest

    const unsigned long long below = (1ull << lane) - 1ull;
    int base = 0;
#pragma unroll
    for (int j = 0; j < 16; ++j) {
        bool sel = (d[j] <= T);
        unsigned long long mask = __ballot(sel);
        if (sel) {
            int pos = base + (int)__popcll(mask & below);
            if (pos < 64)
                cand[pos] = ((unsigned long long)d[j] << 32) | (unsigned)(j * 64 + lane);
        }
        base += (int)__popcll(mask);
    }

    if (base <= 64) {
        unsigned long long v = (lane < base) ? cand[lane] : ~0ull;
        unsigned hi = (unsigned)(v >> 32);
        unsigned hs = wave_bitonic_sort_u32(hi, lane);
        unsigned t2 = (unsigned)__shfl((int)hs, 19, 64);
        bool sel2 = (lane < base) && (hi <= t2);
        unsigned long long m2 = __ballot(sel2);
        if ((int)__popcll(m2) == KNN) {
            if (sel2) out[(int)__popcll(m2 & below)] = (int)(v & 0xffffffffu);
        } else {
            unsigned long long sv = wave_bitonic_sort(v, lane);
            if (lane < KNN) out[lane] = (int)(sv & 0xffffffffu);
        }
    } else {
        u64x16 k;
#pragma unroll
        for (int j = 0; j < 16; ++j)
            k[j] = ((unsigned long long)d[j] << 32) | (unsigned)(j * 64 + lane);
        topk20_wave(k, lane, out);
    }
}

// ---------------- weight-conversion helpers ----------------
static __device__ __forceinline__ void pack_store(unsigned short h[8],
                                                  unsigned short l[8], size_t ci,
                                                  unsigned short* __restrict__ Wh,
                                                  unsigned short* __restrict__ Wl) {
    uint4 hp, lp;
    hp.x = h[0] | ((unsigned)h[1] << 16);
    hp.y = h[2] | ((unsigned)h[3] << 16);
    hp.z = h[4] | ((unsigned)h[5] << 16);
    hp.w = h[6] | ((unsigned)h[7] << 16);
    lp.x = l[0] | ((unsigned)l[1] << 16);
    lp.y = l[2] | ((unsigned)l[3] << 16);
    lp.z = l[4] | ((unsigned)l[5] << 16);
    lp.w = l[6] | ((unsigned)l[7] << 16);
    ((uint4*)Wh)[ci] = hp;
    ((uint4*)Wl)[ci] = lp;
}

static __device__ void conv_edge_w(const float* __restrict__ W, int Cin, int Cout,
                                   int g, unsigned short* __restrict__ Wh,
                                   unsigned short* __restrict__ Wl) {
    int N2 = 2 * Cout;
    if (g >= (Cin / 8) * N2) return;
    int n = g % N2, ks = g / N2;
    unsigned short h[8], l[8];
#pragma unroll
    for (int j = 0; j < 8; ++j) {
        int c = ks * 8 + j;
        float v;
        if (n < Cout)
            v = W[(size_t)c * Cout + n] - W[(size_t)(Cin + c) * Cout + n];
        else
            v = W[(size_t)(Cin + c) * Cout + (n - Cout)];
        split_bf16(v, h[j], l[j]);
    }
    pack_store(h, l, (size_t)ks * N2 + n, Wh, Wl);
}

// ---------------- LDS overlays ----------------
struct Knn3Shared {
    float sx[3][1024];
    float ssq[1024];
    unsigned long long cand[4][64];
};
struct Edge1Shared {
    float sX[3][68];
    float sW[3][132];
};
union L1Shared {
    Knn3Shared k;
    Edge1Shared e;
};

struct KnnShared {
    float sD[16][1028];
    float sqa[16];
    float sqb[1024];
    unsigned long long cand[4][64];
};
struct EdgeShared {
    uint4 sAh[2][4][132];
    uint4 sAl[2][4][132];
    uint4 sBh[2][4][132];
    uint4 sBl[2][4][132];
};
union LayerShared {
    KnnShared k;
    EdgeShared e;
};

struct PoolShared {
    uint4 sAh[2][4][132];
    uint4 sAl[2][4][132];
    uint4 sBh[2][4][132];
    uint4 sBl[2][4][132];
    float sMax[2][128];
};
struct CmGmShared {
    float sred[256];
    float scm[512];
    float4 part[8][32];
};
union PoolUnion {
    PoolShared p;
    CmGmShared c;
};

// ---------------- merged: knn3 (0-511) + f32 edge GEMM (512-639) + W-converts -------
__global__ __launch_bounds__(256) void knn3_edge_conv_kernel(
        const float* __restrict__ x, const float* __restrict__ W,
        const float* __restrict__ bias, int* __restrict__ idx, float* __restrict__ AB,
        const float* __restrict__ Wm, const float* __restrict__ W2,
        const float* __restrict__ W3, const float* __restrict__ W4,
        unsigned short* __restrict__ Wmh, unsigned short* __restrict__ Wml,
        unsigned short* __restrict__ W2h, unsigned short* __restrict__ W2l,
        unsigned short* __restrict__ W3h, unsigned short* __restrict__ W3l,
        unsigned short* __restrict__ W4h, unsigned short* __restrict__ W4l) {
    __shared__ L1Shared su;
    const int bid = blockIdx.x;
    const int tid = threadIdx.x;

    if (bid < 512) {
        // ---- kNN, 16 points per block ----
        Knn3Shared& S = su.k;
        const int wid = tid >> 6, lane = tid & 63;
        const int b = bid >> 6, p0 = (bid & 63) * 16;
        const int g0 = b * NP;
        const float* xb = x + (size_t)g0 * 3;

        for (int t = tid; t < 1024; t += 256) {
            float vx = xb[t * 3 + 0], vy = xb[t * 3 + 1], vz = xb[t * 3 + 2];
            S.sx[0][t] = vx;
            S.sx[1][t] = vy;
            S.sx[2][t] = vz;
            S.ssq[t] = vx * vx + vy * vy + vz * vz;  // ascending-c order
        }
        __syncthreads();

        for (int rr = 0; rr < 4; ++rr) {
            int pr = p0 + wid * 4 + rr;
            const float px = S.sx[0][pr], py = S.sx[1][pr], pz = S.sx[2][pr];
            const float sqp = S.ssq[pr];
            u32x16 d;
#pragma unroll
            for (int j = 0; j < 16; ++j) {
                int q = j * 64 + lane;
                float dot = px * S.sx[0][q];
                dot += py * S.sx[1][q];
                dot += pz * S.sx[2][q];
                float dv = sqp + S.ssq[q] - 2.0f * dot;
                unsigned u = __float_as_uint(dv);
                d[j] = (u & 0x80000000u) ? ~u : (u | 0x80000000u);
            }
            topk20_sel(d, lane, S.cand[wid], idx + (size_t)(g0 + pr) * KNN);
        }
    } else if (bid < 640) {
        // ---- f32 edge GEMM <3,64>: AB[p, 0:64]=x.(W1-W2)+b, [64:128]=x.W2 ----
        Edge1Shared& S = su.e;
        constexpr int Cin = 3, Cout = 64, N2 = 128;
        const int p0 = (bid - 512) * 64;
        const int tx = tid & 15, ty = tid >> 4;

        for (int t = tid; t < 64 * Cin; t += 256) {
            int m = t / Cin, c = t - m * Cin;
            S.sX[c][m] = x[(size_t)(p0 + m) * Cin + c];
        }
        for (int t = tid; t < Cin * 128; t += 256) {
            int c = t >> 7, n = t & 127;
            float w;
            if (n < Cout)
                w = W[(size_t)c * Cout + n] - W[(size_t)(Cin + c) * Cout + n];
            else
                w = W[(size_t)(Cin + c) * Cout + (n - Cout)];
            S.sW[c][n] = w;
        }
        __syncthreads();

        float acc[4][8];
#pragma unroll
        for (int i = 0; i < 4; ++i)
#pragma unroll
            for (int j = 0; j < 8; ++j) acc[i][j] = 0.f;

#pragma unroll
        for (int c = 0; c < Cin; ++c) {
            float4 a4 = *(const float4*)&S.sX[c][ty * 4];
            float4 w0 = *(const float4*)&S.sW[c][tx * 4];
            float4 w1 = *(const float4*)&S.sW[c][64 + tx * 4];
            float av[4] = {a4.x, a4.y, a4.z, a4.w};
#pragma unroll
            for (int i = 0; i < 4; ++i) {
                acc[i][0] += av[i] * w0.x;
                acc[i][1] += av[i] * w0.y;
                acc[i][2] += av[i] * w0.z;
                acc[i][3] += av[i] * w0.w;
                acc[i][4] += av[i] * w1.x;
                acc[i][5] += av[i] * w1.y;
                acc[i][6] += av[i] * w1.z;
                acc[i][7] += av[i] * w1.w;
            }
        }

        float4 bb0 = *(const float4*)&bias[tx * 4];
#pragma unroll
        for (int i = 0; i < 4; ++i) {
            float* orow = AB + (size_t)(p0 + ty * 4 + i) * N2;
            float4 o0, o1;
            o0.x = acc[i][0] + bb0.x;
            o0.y = acc[i][1] + bb0.y;
            o0.z = acc[i][2] + bb0.z;
            o0.w = acc[i][3] + bb0.w;
            o1.x = acc[i][4];
            o1.y = acc[i][5];
            o1.z = acc[i][6];
            o1.w = acc[i][7];
            *(float4*)&orow[tx * 4] = o0;
            *(float4*)&orow[64 + tx * 4] = o1;
        }
    } else {
        // ---- weight conversions (data-independent of pos) ----
        int cid = bid - 640;
        if (cid < 256) {
            int g = cid * 256 + tid;  // 65536 Wm jobs
            int n = g & 1023, ks = g >> 10;
            unsigned short h[8], l[8];
#pragma unroll
            for (int j = 0; j < 8; ++j) {
                float v = Wm[(size_t)(ks * 8 + j) * 1024 + n];
                split_bf16(v, h[j], l[j]);
            }
            pack_store(h, l, (size_t)ks * 1024 + n, Wmh, Wml);
        } else if (cid < 288) {
            conv_edge_w(W4, 128, 256, (cid - 256) * 256 + tid, W4h, W4l);
        } else if (cid < 296) {
            conv_edge_w(W3, 64, 128, (cid - 288) * 256 + tid, W3h, W3l);
        } else {
            conv_edge_w(W2, 64, 64, (cid - 296) * 256 + tid, W2h, W2l);
        }
    }
}

// ---------------- merged layer kernel: MFMA knn (blocks 0-511) + MFMA edge GEMM -----
template <int C, int Cout>
__global__ __launch_bounds__(256, 2) void layer_kernel(
        const unsigned short* __restrict__ Xhp, const unsigned short* __restrict__ Xlp,
        const float* __restrict__ sqn, int* __restrict__ idx,
        const unsigned short* __restrict__ Whp, const unsigned short* __restrict__ Wlp,
        const float* __restrict__ bias, float* __restrict__ AB) {
    __shared__ LayerShared su;
    constexpr int NCK = C / 32;
    const int bid = blockIdx.x;
    const int tid = threadIdx.x;
    const int wid = tid >> 6, lane = tid & 63;
    const int fkb = lane >> 4, flm = lane & 15;
    const uint4* Ah4 = (const uint4*)Xhp;
    const uint4* Al4 = (const uint4*)Xlp;

    if (bid < 512) {
        // ---- fused MFMA dist + top-20 ----
        KnnShared& S = su.k;
        const int b = bid >> 6, rg = bid & 63;
        const int g0 = b * NP;
        const int p0 = rg * 16;

        if (tid < 16) S.sqa[tid] = sqn[g0 + p0 + tid];
        for (int t = tid; t < 1024; t += 256) S.sqb[t] = sqn[g0 + t];
        __syncthreads();

        uint4 fAh[NCK], fAl[NCK];
#pragma unroll
        for (int kk = 0; kk < NCK; ++kk) {
            size_t a = (size_t)(4 * kk + fkb) * NPTS + g0 + p0 + flm;
            fAh[kk] = Ah4[a];
            fAl[kk] = Al4[a];
        }

        const int r4 = fkb * 4, cc = flm;

#pragma unroll
        for (int t = 0; t < 2; ++t) {
            const int c0 = (wid + t * 4) * 128;
            f32x4 acc[8];
#pragma unroll
            for (int j = 0; j < 8; ++j) acc[j] = {0.f, 0.f, 0.f, 0.f};

#pragma unroll
            for (int kk = 0; kk < NCK; ++kk) {
                uint4 fBh[8], fBl[8];
#pragma unroll
                for (int j = 0; j < 8; ++j) {
                    size_t bi = (size_t)(4 * kk + fkb) * NPTS + g0 + c0 + j * 16 + flm;
                    fBh[j] = Ah4[bi];
                    fBl[j] = Al4[bi];
                }
                bf16x8 ah = *(const bf16x8*)&fAh[kk];
                bf16x8 al = *(const bf16x8*)&fAl[kk];
#pragma unroll
                for (int j = 0; j < 8; ++j) {
                    bf16x8 bh = *(const bf16x8*)&fBh[j];
                    bf16x8 bl = *(const bf16x8*)&fBl[j];
                    acc[j] = __builtin_amdgcn_mfma_f32_16x16x32_bf16(ah, bh, acc[j], 0, 0, 0);
                    acc[j] = __builtin_amdgcn_mfma_f32_16x16x32_bf16(ah, bl, acc[j], 0, 0, 0);
                    acc[j] = __builtin_amdgcn_mfma_f32_16x16x32_bf16(al, bh, acc[j], 0, 0, 0);
                }
            }

#pragma unroll
            for (int r = 0; r < 4; ++r) {
                int row = r4 + r;
                float sp = S.sqa[row];
#pragma unroll
                for (int j = 0; j < 8; ++j) {
                    int col = c0 + j * 16 + cc;
                    S.sD[row][col] = sp + S.sqb[col] - 2.0f * acc[j][r];
                }
            }
        }
        __syncthreads();

        for (int rr = 0; rr < 4; ++rr) {
            int row = wid * 4 + rr;
            u32x16 d;
#pragma unroll
            for (int j = 0; j < 16; ++j) {
                int q = j * 64 + lane;
                unsigned u = __float_as_uint(S.sD[row][q]);
                d[j] = (u & 0x80000000u) ? ~u : (u | 0x80000000u);
            }
            topk20_sel(d, lane, S.cand[wid], idx + (size_t)(g0 + p0 + row) * KNN);
        }
    } else {
        // ---- MFMA split-bf16 edge GEMM ----
        EdgeShared& S = su.e;
        constexpr int N2 = 2 * Cout;
        constexpr int NX = N2 / 128;
        const int eb = bid - 512;
        const int n0 = (eb % NX) * 128;
        const int p0 = (eb / NX) * 128;
        const int wm = (wid >> 1) * 64, wn = (wid & 1) * 64;

        f32x4 acc[4][4];
#pragma unroll
        for (int i = 0; i < 4; ++i)
#pragma unroll
            for (int j = 0; j < 4; ++j) acc[i][j] = {0.f, 0.f, 0.f, 0.f};

        const uint4* Wh4 = (const uint4*)Whp;
        const uint4* Wl4 = (const uint4*)Wlp;

        const int m0 = tid & 127, kb0 = tid >> 7;
        uint4 rAh0, rAl0, rBh0, rBl0, rAh1, rAl1, rBh1, rBl1;

#define EM_LOAD(ck)                                                     \
    {                                                                   \
        int ksb = (ck) * 4;                                             \
        size_t a0 = (size_t)(ksb + kb0) * NPTS + p0 + m0;               \
        size_t a1 = (size_t)(ksb + kb0 + 2) * NPTS + p0 + m0;           \
        size_t b0 = (size_t)(ksb + kb0) * N2 + n0 + m0;                 \
        size_t b1 = (size_t)(ksb + kb0 + 2) * N2 + n0 + m0;             \
        rAh0 = Ah4[a0]; rAl0 = Al4[a0];                                 \
        rAh1 = Ah4[a1]; rAl1 = Al4[a1];                                 \
        rBh0 = Wh4[b0]; rBl0 = Wl4[b0];                                 \
        rBh1 = Wh4[b1]; rBl1 = Wl4[b1];                                 \
    }

#define EM_WRITE(buf)                                                         \
    {                                                                         \
        S.sAh[buf][kb0][m0] = rAh0;  S.sAl[buf][kb0][m0] = rAl0;              \
        S.sAh[buf][kb0 + 2][m0] = rAh1;  S.sAl[buf][kb0 + 2][m0] = rAl1;      \
        S.sBh[buf][kb0][m0] = rBh0;  S.sBl[buf][kb0][m0] = rBl0;              \
        S.sBh[buf][kb0 + 2][m0] = rBh1;  S.sBl[buf][kb0 + 2][m0] = rBl1;      \
    }

        EM_LOAD(0);
        EM_WRITE(0);
        __syncthreads();

        for (int ck = 0; ck < NCK; ++ck) {
            const int buf = ck & 1;
            if (ck < NCK - 1) EM_LOAD(ck + 1);

            bf16x8 fAh[4], fAl[4], fBh[4], fBl[4];
#pragma unroll
            for (int i = 0; i < 4; ++i) {
                fAh[i] = *(const bf16x8*)&S.sAh[buf][fkb][wm + i * 16 + flm];
                fAl[i] = *(const bf16x8*)&S.sAl[buf][fkb][wm + i * 16 + flm];
                fBh[i] = *(const bf16x8*)&S.sBh[buf][fkb][wn + i * 16 + flm];
                fBl[i] = *(const bf16x8*)&S.sBl[buf][fkb][wn + i * 16 + flm];
            }
#pragma unroll
            for (int i = 0; i < 4; ++i)
#pragma unroll
                for (int j = 0; j < 4; ++j) {
                    acc[i][j] = __builtin_amdgcn_mfma_f32_16x16x32_bf16(
                            fAh[i], fBh[j], acc[i][j], 0, 0, 0);
                    acc[i][j] = __builtin_amdgcn_mfma_f32_16x16x32_bf16(
                            fAh[i], fBl[j], acc[i][j], 0, 0, 0);
                    acc[i][j] = __builtin_amdgcn_mfma_f32_16x16x32_bf16(
                            fAl[i], fBh[j], acc[i][j], 0, 0, 0);
                }

            if (ck < NCK - 1) EM_WRITE(buf ^ 1);
            __syncthreads();
        }

        const int r4 = (lane >> 4) * 4, cc = lane & 15;
        float bj[4];
#pragma unroll
        for (int j = 0; j < 4; ++j) {
            int cg = n0 + wn + j * 16 + cc;
            bj[j] = (cg < Cout) ? bias[cg] : 0.f;
        }
#pragma unroll
        for (int i = 0; i < 4; ++i) {
#pragma unroll
            for (int r = 0; r < 4; ++r) {
                int row = wm + i * 16 + r4 + r;
                float* orow = AB + (size_t)(p0 + row) * N2 + n0;
#pragma unroll
                for (int j = 0; j < 4; ++j)
                    orow[wn + j * 16 + cc] = acc[i][j][r] + bj[j];
            }
        }
#undef EM_LOAD
#undef EM_WRITE
    }
}

// ---------------- gather-max + panel write + (optional) exact sqnorm ----------------
template <int Cout, bool WSQ>
__global__ __launch_bounds__(256) void gather_max_panel_kernel(
        const float* __restrict__ AB, const int* __restrict__ idx,
        float* __restrict__ y, unsigned short* __restrict__ Xh,
        unsigned short* __restrict__ Xl, float* __restrict__ sqn) {
    constexpr int N2 = 2 * Cout;
    constexpr int TPP = Cout / 4;
    constexpr int PPB = 256 / TPP;
    constexpr int RS = N2 / 4;
    const int pp = threadIdx.x / TPP;
    const int t = threadIdx.x % TPP;
    const int p = blockIdx.x * PPB + pp;
    const int base = p & ~(NP - 1);

    __shared__ int s_idx[PPB][KNN];
    __shared__ float srow[PPB][Cout];
    for (int tt = threadIdx.x; tt < PPB * KNN; tt += 256) {
        int a = tt / KNN, r = tt - a * KNN;
        s_idx[a][r] = idx[(size_t)(blockIdx.x * PPB + a) * KNN + r];
    }
    __syncthreads();

    const float4* Brow = (const float4*)(AB + (size_t)base * N2 + Cout);

    int q0 = s_idx[pp][0];
    float4 m = Brow[(size_t)q0 * RS + t];
#pragma unroll
    for (int j = 1; j < KNN; ++j) {
        int q = s_idx[pp][j];
        float4 v = Brow[(size_t)q * RS + t];
        m.x = fmaxf(m.x, v.x);
        m.y = fmaxf(m.y, v.y);
        m.z = fmaxf(m.z, v.z);
        m.w = fmaxf(m.w, v.w);
    }
    float4 a = *(const float4*)(AB + (size_t)p * N2 + 4 * t);
    float4 o;
    o.x = a.x + m.x;
    o.y = a.y + m.y;
    o.z = a.z + m.z;
    o.w = a.w + m.w;
    *(float4*)(y + (size_t)p * Cout + 4 * t) = o;

    // fused panel write: channels 4t..4t+3 -> ks = t>>1, half (t&1)
    unsigned short h[4], l[4];
    split_bf16(o.x, h[0], l[0]);
    split_bf16(o.y, h[1], l[1]);
    split_bf16(o.z, h[2], l[2]);
    split_bf16(o.w, h[3], l[3]);
    const int ks = t >> 1;
    size_t u2 = ((size_t)ks * NPTS + p) * 2 + (t & 1);
    uint2 hp, lp;
    hp.x = h[0] | ((unsigned)h[1] << 16);
    hp.y = h[2] | ((unsigned)h[3] << 16);
    lp.x = l[0] | ((unsigned)l[1] << 16);
    lp.y = l[2] | ((unsigned)l[3] << 16);
    ((uint2*)Xh)[u2] = hp;
    ((uint2*)Xl)[u2] = lp;

    if constexpr (WSQ) {
        // exact sqnorm: same ascending-c serial sum as the old sqnorm_kernel
        *(float4*)&srow[pp][4 * t] = o;
        __syncthreads();
        if (t == 0) {
            float s = 0.f;
            for (int c = 0; c < Cout; ++c) {
                float v = srow[pp][c];
                s += v * v;
            }
            sqn[p] = s;
        }
    }
}

// ---------------- merged: MFMA cat-GEMM + max pool (0-511) + catmean->gmean (512-519)
__global__ __launch_bounds__(256, 2) void gemm_cat_pool_cm_kernel(
        const unsigned short* __restrict__ Ahp, const unsigned short* __restrict__ Alp,
        const unsigned short* __restrict__ Whp, const unsigned short* __restrict__ Wlp,
        float* __restrict__ pmax, const float* __restrict__ x1,
        const float* __restrict__ x2, const float* __restrict__ x3,
        const float* __restrict__ x4, const float* __restrict__ Wm,
        const float* __restrict__ bm, float* __restrict__ gmeanv) {
    __shared__ PoolUnion su;
    const int bid = blockIdx.x;
    const int tid = threadIdx.x;

    if (bid < 512) {
        PoolShared& S = su.p;
        const int xcd = bid & 7, pos = bid >> 3;
        const int nb = pos & 7, pb = (xcd << 3) | (pos >> 3);
        const int n0 = nb * 128, p0 = pb * 128;
        const int wid = tid >> 6, lane = tid & 63;
        const int wm = (wid >> 1) * 64, wn = (wid & 1) * 64;

        f32x4 acc[4][4];
#pragma unroll
        for (int i = 0; i < 4; ++i)
#pragma unroll
            for (int j = 0; j < 4; ++j) acc[i][j] = {0.f, 0.f, 0.f, 0.f};

        const uint4* Ah4 = (const uint4*)Ahp;
        const uint4* Al4 = (const uint4*)Alp;
        const uint4* Wh4 = (const uint4*)Whp;
        const uint4* Wl4 = (const uint4*)Wlp;

        const int m0 = tid & 127, kb0 = tid >> 7;
        uint4 rAh0, rAl0, rBh0, rBl0, rAh1, rAl1, rBh1, rBl1;

#define MP_LOAD(ck)                                                     \
    {                                                                   \
        int ksb = (ck) * 4;                                             \
        size_t a0 = (size_t)(ksb + kb0) * 8192 + p0 + m0;               \
        size_t a1 = (size_t)(ksb + kb0 + 2) * 8192 + p0 + m0;           \
        size_t b0 = (size_t)(ksb + kb0) * 1024 + n0 + m0;               \
        size_t b1 = (size_t)(ksb + kb0 + 2) * 1024 + n0 + m0;           \
        rAh0 = Ah4[a0]; rAl0 = Al4[a0];                                 \
        rAh1 = Ah4[a1]; rAl1 = Al4[a1];                                 \
        rBh0 = Wh4[b0]; rBl0 = Wl4[b0];                                 \
        rBh1 = Wh4[b1]; rBl1 = Wl4[b1];                                 \
    }

#define MP_WRITE(buf)                                                         \
    {                                                                         \
        S.sAh[buf][kb0][m0] = rAh0;  S.sAl[buf][kb0][m0] = rAl0;              \
        S.sAh[buf][kb0 + 2][m0] = rAh1;  S.sAl[buf][kb0 + 2][m0] = rAl1;      \
        S.sBh[buf][kb0][m0] = rBh0;  S.sBl[buf][kb0][m0] = rBl0;              \
        S.sBh[buf][kb0 + 2][m0] = rBh1;  S.sBl[buf][kb0 + 2][m0] = rBl1;      \
    }

        MP_LOAD(0);
        MP_WRITE(0);
        __syncthreads();

        const int fkb = lane >> 4, flm = lane & 15;

        for (int ck = 0; ck < 16; ++ck) {
            const int buf = ck & 1;
            if (ck < 15) MP_LOAD(ck + 1);

            bf16x8 fAh[4], fAl[4], fBh[4], fBl[4];
#pragma unroll
            for (int i = 0; i < 4; ++i) {
                fAh[i] = *(const bf16x8*)&S.sAh[buf][fkb][wm + i * 16 + flm];
                fAl[i] = *(const bf16x8*)&S.sAl[buf][fkb][wm + i * 16 + flm];
                fBh[i] = *(const bf16x8*)&S.sBh[buf][fkb][wn + i * 16 + flm];
                fBl[i] = *(const bf16x8*)&S.sBl[buf][fkb][wn + i * 16 + flm];
            }
#pragma unroll
            for (int i = 0; i < 4; ++i)
#pragma unroll
                for (int j = 0; j < 4; ++j) {
                    acc[i][j] = __builtin_amdgcn_mfma_f32_16x16x32_bf16(
                            fAh[i], fBh[j], acc[i][j], 0, 0, 0);
                    acc[i][j] = __builtin_amdgcn_mfma_f32_16x16x32_bf16(
                            fAh[i], fBl[j], acc[i][j], 0, 0, 0);
                    acc[i][j] = __builtin_amdgcn_mfma_f32_16x16x32_bf16(
                            fAl[i], fBh[j], acc[i][j], 0, 0, 0);
                }

            if (ck < 15) MP_WRITE(buf ^ 1);
            __syncthreads();
        }

        float cm[4];
#pragma unroll
        for (int j = 0; j < 4; ++j) {
            float m = acc[0][j][0];
#pragma unroll
            for (int i = 0; i < 4; ++i)
#pragma unroll
                for (int r = 0; r < 4; ++r) m = fmaxf(m, acc[i][j][r]);
            m = fmaxf(m, __shfl_xor(m, 16, 64));
            m = fmaxf(m, __shfl_xor(m, 32, 64));
            cm[j] = m;
        }
        if (lane < 16) {
#pragma unroll
            for (int j = 0; j < 4; ++j) S.sMax[wid >> 1][wn + j * 16 + lane] = cm[j];
        }
        __syncthreads();
        if (tid < 128)
            pmax[(size_t)pb * 1024 + n0 + tid] = fmaxf(S.sMax[0][tid], S.sMax[1][tid]);
#undef MP_LOAD
#undef MP_WRITE
    } else {
        // ---- catmean (bitwise-identical) then gmean (bitwise-identical), 1 cloud ----
        CmGmShared& S = su.c;
        const int b = bid - 512;

        for (int n0 = 0; n0 < 512; n0 += 128) {
            const int col = n0 + (tid & 127);
            const int half = tid >> 7;
            const float* src;
            int cw, coff;
            if (col < 64) { src = x1; cw = 64; coff = col; }
            else if (col < 128) { src = x2; cw = 64; coff = col - 64; }
            else if (col < 256) { src = x3; cw = 128; coff = col - 128; }
            else { src = x4; cw = 256; coff = col - 256; }

            float s = 0.f;
            const float* base = src + ((size_t)b * NP + half * 512) * cw + coff;
            for (int p = 0; p < 512; ++p) s += base[(size_t)p * cw];
            S.sred[tid] = s;
            __syncthreads();
            if (tid < 128)
                S.scm[n0 + tid] = (S.sred[tid] + S.sred[tid + 128]) * (1.0f / 1024.0f);
            __syncthreads();
        }

        for (int n0 = 0; n0 < 1024; n0 += 128) {
            const int cg = tid & 31, kp = tid >> 5;
            const int col = n0 + cg * 4;
            float4 acc = {0.f, 0.f, 0.f, 0.f};
            for (int k = kp * 64; k < kp * 64 + 64; ++k) {
                float g = S.scm[k];
                float4 w = *(const float4*)&Wm[(size_t)k * 1024 + col];
                acc.x += g * w.x;
                acc.y += g * w.y;
                acc.z += g * w.z;
                acc.w += g * w.w;
            }
            S.part[kp][cg] = acc;
            __syncthreads();
            if (tid < 32) {
                float4 s = S.part[0][tid];
#pragma unroll
                for (int z = 1; z < 8; ++z) {
                    float4 p = S.part[z][tid];
                    s.x += p.x; s.y += p.y; s.z += p.z; s.w += p.w;
                }
                float4 bb = *(const float4*)&bm[n0 + tid * 4];
                s.x += bb.x; s.y += bb.y; s.z += bb.z; s.w += bb.w;
                *(float4*)&gmeanv[(size_t)b * 1024 + n0 + tid * 4] = s;
            }
            __syncthreads();
        }
    }
}

// ---------------- fc_a ----------------
__global__ __launch_bounds__(256) void fc_a_kernel(const float* __restrict__ pmax,
                                                   const float* __restrict__ gmeanv,
                                                   const float* __restrict__ bm,
                                                   const float* __restrict__ Wa,
                                                   const float* __restrict__ ba,
                                                   float* __restrict__ ha) {
    const int b = blockIdx.y;
    const int n0 = blockIdx.x * 64;
    const int tid = threadIdx.x;
    __shared__ float gm[2048];
    __shared__ float4 part[16][16];

    for (int c = tid; c < 1024; c += 256) {
        float m = pmax[(size_t)(b * 8) * 1024 + c];
#pragma unroll
        for (int z = 1; z < 8; ++z) m = fmaxf(m, pmax[(size_t)(b * 8 + z) * 1024 + c]);
        gm[c] = m + bm[c];
        gm[1024 + c] = gmeanv[(size_t)b * 1024 + c];
    }
    __syncthreads();

    const int cg = tid & 15, kp = tid >> 4;
    const int co = n0 + cg * 4;
    float4 acc = {0.f, 0.f, 0.f, 0.f};
    const float* Wp = Wa + (size_t)(kp * 128) * 512 + co;
    const float* gp = gm + kp * 128;
#pragma unroll 8
    for (int k = 0; k < 128; ++k) {
        float g = gp[k];
        float4 w = *(const float4*)&Wp[(size_t)k * 512];
        acc.x += g * w.x;
        acc.y += g * w.y;
        acc.z += g * w.z;
        acc.w += g * w.w;
    }
    part[kp][cg] = acc;
    __syncthreads();
    if (tid < 16) {
        float4 s = part[0][tid];
#pragma unroll
        for (int z = 1; z < 16; ++z) {
            float4 p = part[z][tid];
            s.x += p.x; s.y += p.y; s.z += p.z; s.w += p.w;
        }
        float4 bb = *(const float4*)&ba[n0 + tid * 4];
        s.x += bb.x; s.y += bb.y; s.z += bb.z; s.w += bb.w;
        *(float4*)&ha[(size_t)b * 512 + n0 + tid * 4] = s;
    }
}

// ---------------- fc_b with fused batchnorm+leaky on input ----------------
__global__ __launch_bounds__(256) void fc_b_bn_kernel(const float* __restrict__ ha,
                                                      const float* __restrict__ g,
                                                      const float* __restrict__ be,
                                                      const float* __restrict__ Wb,
                                                      const float* __restrict__ bb,
                                                      float* __restrict__ hb) {
    const int b = blockIdx.y;
    const int n0 = blockIdx.x * 64;
    const int tid = threadIdx.x;
    __shared__ float shall[NB][512];
    __shared__ float sh[512];
    __shared__ float4 part[16][16];

    for (int t = tid; t < NB * 512; t += 256) shall[t >> 9][t & 511] = ha[t];
    __syncthreads();

    for (int c = tid; c < 512; c += 256) {
        float mu = 0.f;
        for (int z = 0; z < NB; ++z) mu += shall[z][c];
        mu *= 0.125f;
        float var = 0.f;
        for (int z = 0; z < NB; ++z) {
            float d = shall[z][c] - mu;
            var += d * d;
        }
        var *= 0.125f;
        float inv = 1.0f / sqrtf(var + 1e-5f);
        float v = (shall[b][c] - mu) * inv * g[c] + be[c];
        sh[c] = v >= 0.f ? v : 0.2f * v;
    }
    __syncthreads();

    const int cg = tid & 15, kp = tid >> 4;
    const int co = n0 + cg * 4;
    float4 acc = {0.f, 0.f, 0.f, 0.f};
#pragma unroll 8
    for (int k = 0; k < 32; ++k) {
        float gg = sh[kp * 32 + k];
        float4 w = *(const float4*)&Wb[(size_t)(kp * 32 + k) * 256 + co];
        acc.x += gg * w.x;
        acc.y += gg * w.y;
        acc.z += gg * w.z;
        acc.w += gg * w.w;
    }
    part[kp][cg] = acc;
    __syncthreads();
    if (tid < 16) {
        float4 s = part[0][tid];
#pragma unroll
        for (int z = 1; z < 16; ++z) {
            float4 p = part[z][tid];
            s.x += p.x; s.y += p.y; s.z += p.z; s.w += p.w;
        }
        float4 bv = *(const float4*)&bb[n0 + tid * 4];
        s.x += bv.x; s.y += bv.y; s.z += bv.z; s.w += bv.w;
        *(float4*)&hb[(size_t)b * 256 + n0 + tid * 4] = s;
    }
}

// ---------------- fc_c with fused batchnorm+leaky on input ----------------
__global__ __launch_bounds__(256) void fc_c_bn_kernel(const float* __restrict__ hbin,
                                                      const float* __restrict__ g,
                                                      const float* __restrict__ be,
                                                      const float* __restrict__ Wc,
                                                      const float* __restrict__ bc,
                                                      float* __restrict__ outp) {
    const int tid = threadIdx.x;
    __shared__ float shn[NB][256];

    {
        int c = tid;  // 256 threads <-> 256 cols
        float col[NB];
#pragma unroll
        for (int z = 0; z < NB; ++z) col[z] = hbin[z * 256 + c];
        float mu = 0.f;
#pragma unroll
        for (int z = 0; z < NB; ++z) mu += col[z];
        mu *= 0.125f;
        float var = 0.f;
#pragma unroll
        for (int z = 0; z < NB; ++z) {
            float d = col[z] - mu;
            var += d * d;
        }
        var *= 0.125f;
        float inv = 1.0f / sqrtf(var + 1e-5f);
#pragma unroll
        for (int z = 0; z < NB; ++z) {
            float v = (col[z] - mu) * inv * g[c] + be[c];
            shn[z][c] = v >= 0.f ? v : 0.2f * v;
        }
    }
    __syncthreads();

    int t = blockIdx.x * 256 + tid;  // 8*40 outputs
    if (t < 8 * 40) {
        int b = t / 40, o = t - b * 40;
        float s = bc[o];
        for (int c = 0; c < 256; ++c) s += shn[b][c] * Wc[c * 40 + o];
        outp[t] = s;
    }
}

extern "C" void kernel_launch(void* const* d_in, const int* in_sizes, int n_in,
                              void* d_out, int out_size, void* d_ws, size_t ws_size,
                              hipStream_t stream) {
    const float* pos = (const float*)d_in[0];
    const float* W1 = (const float*)d_in[2];
    const float* b1 = (const float*)d_in[3];
    const float* W2 = (const float*)d_in[4];
    const float* b2 = (const float*)d_in[5];
    const float* W3 = (const float*)d_in[6];
    const float* b3 = (const float*)d_in[7];
    const float* W4 = (const float*)d_in[8];
    const float* b4 = (const float*)d_in[9];
    const float* Wm = (const float*)d_in[10];
    const float* bm = (const float*)d_in[11];
    const float* Wa = (const float*)d_in[12];
    const float* ba = (const float*)d_in[13];
    const float* ga = (const float*)d_in[14];
    const float* bea = (const float*)d_in[15];
    const float* Wb = (const float*)d_in[16];
    const float* bb = (const float*)d_in[17];
    const float* gb = (const float*)d_in[18];
    const float* beb = (const float*)d_in[19];
    const float* Wc = (const float*)d_in[20];
    const float* bc = (const float*)d_in[21];
    float* out = (float*)d_out;

    char* ws = (char*)d_ws;
    size_t off = 0;
    auto alloc = [&](size_t bytes) {
        void* p = ws + off;
        off += (bytes + 255) & ~(size_t)255;
        return p;
    };
    int* idx = (int*)alloc((size_t)NPTS * KNN * 4);
    float* x1 = (float*)alloc((size_t)NPTS * 64 * 4);
    float* x2 = (float*)alloc((size_t)NPTS * 64 * 4);
    float* x3 = (float*)alloc((size_t)NPTS * 128 * 4);
    float* x4 = (float*)alloc((size_t)NPTS * 256 * 4);
    float* scratch = (float*)alloc((size_t)NPTS * 512 * 4);  // AB (max 8192x512)
    float* pmax = (float*)alloc((size_t)64 * 1024 * 4);
    float* gmeanv = (float*)alloc(NB * 1024 * 4);
    float* ha = (float*)alloc(NB * 512 * 4);
    float* hb = (float*)alloc(NB * 256 * 4);
    float* sqn = (float*)alloc(NPTS * 4);
    // unified cat panels [64][8192][8]: x1 ks0-7, x2 ks8-15, x3 ks16-31, x4 ks32-63
    unsigned short* Ach = (unsigned short*)alloc((size_t)64 * NPTS * 8 * 2);
    unsigned short* Acl = (unsigned short*)alloc((size_t)64 * NPTS * 8 * 2);
    unsigned short* Wth = (unsigned short*)alloc((size_t)64 * 1024 * 8 * 2);
    unsigned short* Wtl = (unsigned short*)alloc((size_t)64 * 1024 * 8 * 2);
    unsigned short* W2h = (unsigned short*)alloc((size_t)8 * 128 * 8 * 2);
    unsigned short* W2l = (unsigned short*)alloc((size_t)8 * 128 * 8 * 2);
    unsigned short* W3h = (unsigned short*)alloc((size_t)8 * 256 * 8 * 2);
    unsigned short* W3l = (unsigned short*)alloc((size_t)8 * 256 * 8 * 2);
    unsigned short* W4h = (unsigned short*)alloc((size_t)16 * 512 * 8 * 2);
    unsigned short* W4l = (unsigned short*)alloc((size_t)16 * 512 * 8 * 2);
    (void)ws_size;

    float* AB = scratch;
    const size_t REG = (size_t)NPTS * 8;  // ushorts per ks-chunk
    unsigned short* x1h = Ach, *x1l = Acl;
    unsigned short* x2h = Ach + 8 * REG, *x2l = Acl + 8 * REG;
    unsigned short* x3h = Ach + 16 * REG, *x3l = Acl + 16 * REG;
    unsigned short* x4h = Ach + 32 * REG, *x4l = Acl + 32 * REG;

    // layer 1: kNN + f32 edge GEMM + ALL weight conversions (one launch, 940 blocks)
    knn3_edge_conv_kernel<<<940, 256, 0, stream>>>(pos, W1, b1, idx, AB, Wm, W2, W3,
                                                   W4, Wth, Wtl, W2h, W2l, W3h, W3l,
                                                   W4h, W4l);
    gather_max_panel_kernel<64, true><<<NPTS / 16, 256, 0, stream>>>(AB, idx, x1, x1h,
                                                                     x1l, sqn);

    // layer 2: merged MFMA knn + edge GEMM, then gather (+sqn of x2)
    layer_kernel<64, 64><<<512 + 64, 256, 0, stream>>>(x1h, x1l, sqn, idx, W2h, W2l,
                                                       b2, AB);
    gather_max_panel_kernel<64, true><<<NPTS / 16, 256, 0, stream>>>(AB, idx, x2, x2h,
                                                                     x2l, sqn);

    // layer 3
    layer_kernel<64, 128><<<512 + 128, 256, 0, stream>>>(x2h, x2l, sqn, idx, W3h, W3l,
                                                         b3, AB);
    gather_max_panel_kernel<128, true><<<NPTS / 8, 256, 0, stream>>>(AB, idx, x3, x3h,
                                                                     x3l, sqn);

    // layer 4 (no sqn needed for x4)
    layer_kernel<128, 256><<<512 + 256, 256, 0, stream>>>(x3h, x3l, sqn, idx, W4h, W4l,
                                                          b4, AB);
    gather_max_panel_kernel<256, false><<<NPTS / 4, 256, 0, stream>>>(AB, idx, x4, x4h,
                                                                      x4l, nullptr);

    // MFMA cat-GEMM + max pool (0-511) + catmean->gmean (512-519), one launch
    gemm_cat_pool_cm_kernel<<<520, 256, 0, stream>>>(Ach, Acl, Wth, Wtl, pmax, x1, x2,
                                                     x3, x4, Wm, bm, gmeanv);

    // head
    fc_a_kernel<<<dim3(8, NB), 256, 0, stream>>>(pmax, gmeanv, bm, Wa, ba, ha);
    fc_b_bn_kernel<<<dim3(4, NB), 256, 0, stream>>>(ha, ga, bea, Wb, bb, hb);
    fc_c_bn_kernel<<<2, 256, 0, stream>>>(hb, gb, beb, Wc, bc, out);
}

// Round 18
// 216.939 us; speedup vs baseline: 1.1787x; 1.1787x over previous
//
#include <hip/hip_runtime.h>
#include <hip/hip_bf16.h>

#define NB 8
#define NP 1024
#define NPTS (NB * NP)
#define KNN 20

using bf16x8 = __attribute__((ext_vector_type(8))) short;
using f32x4 = __attribute__((ext_vector_type(4))) float;
using u64x16 = __attribute__((ext_vector_type(16))) unsigned long long;
using u32x16 = __attribute__((ext_vector_type(16))) unsigned int;

static __device__ __forceinline__ unsigned long long umin64(unsigned long long a,
                                                            unsigned long long b) {
    return a < b ? a : b;
}

static __device__ __forceinline__ void split_bf16(float v, unsigned short& h,
                                                  unsigned short& l) {
    __hip_bfloat16 hb = __float2bfloat16(v);
    float hf = __bfloat162float(hb);
    __hip_bfloat16 lb = __float2bfloat16(v - hf);
    h = *(unsigned short*)&hb;
    l = *(unsigned short*)&lb;
}

// ---------------- wave-wide bitonic sorts (64 lanes, ascending) ----------
static __device__ __forceinline__ unsigned long long wave_bitonic_sort(
        unsigned long long v, int lane) {
#pragma unroll
    for (int k = 2; k <= 64; k <<= 1) {
#pragma unroll
        for (int j = k >> 1; j > 0; j >>= 1) {
            unsigned long long o = __shfl_xor(v, j, 64);
            bool tmin = (((lane & k) == 0) == ((lane & j) == 0));
            bool lt = v < o;
            v = (lt == tmin) ? v : o;
        }
    }
    return v;
}

static __device__ __forceinline__ unsigned wave_bitonic_sort_u32(unsigned v, int lane) {
#pragma unroll
    for (int k = 2; k <= 64; k <<= 1) {
#pragma unroll
        for (int j = k >> 1; j > 0; j >>= 1) {
            unsigned o = (unsigned)__shfl_xor((int)v, j, 64);
            bool tmin = (((lane & k) == 0) == ((lane & j) == 0));
            bool lt = v < o;
            v = (lt == tmin) ? v : o;
        }
    }
    return v;
}

// ---------------- wave-local top-20, exact full fallback (flat scan, u64) ----------
static __device__ __forceinline__ void topk20_wave(u64x16 k, int lane,
                                                   int* __restrict__ out) {
    for (int r = 0; r < KNN; ++r) {
        unsigned long long m = k[0];
#pragma unroll
        for (int j = 1; j < 16; ++j)
            if ((unsigned)(k[j] >> 32) < (unsigned)(m >> 32)) m = k[j];
#pragma unroll
        for (int s = 1; s < 64; s <<= 1) {
            unsigned long long o = __shfl_xor(m, s, 64);
            m = umin64(m, o);
        }
        if (lane == 0) out[r] = (int)(m & 0xffffffffu);
        if (r == KNN - 1) break;
        unsigned mlo = (unsigned)m;
#pragma unroll
        for (int j = 0; j < 16; ++j)
            if ((unsigned)k[j] == mlo) k[j] = ~0ull;
    }
}

// ---------------- wave-local top-20 SET selection (unordered output) ----------------
static __device__ __forceinline__ void topk20_sel(u32x16 d, int lane,
                                                  unsigned long long* __restrict__ cand,
                                                  int* __restrict__ out) {
    unsigned lm = d[0];
#pragma unroll
    for (int j = 1; j < 16; ++j) lm = (d[j] < lm) ? d[j] : lm;
    unsigned srt = wave_bitonic_sort_u32(lm, lane);
    unsigned T = (unsigned)__shfl((int)srt, 19, 64);  // upper bound on 20th smallest

    const unsigned long long below = (1ull << lane) - 1ull;
    int base = 0;
#pragma unroll
    for (int j = 0; j < 16; ++j) {
        bool sel = (d[j] <= T);
        unsigned long long mask = __ballot(sel);
        if (sel) {
            int pos = base + (int)__popcll(mask & below);
            if (pos < 64)
                cand[pos] = ((unsigned long long)d[j] << 32) | (unsigned)(j * 64 + lane);
        }
        base += (int)__popcll(mask);
    }

    if (base <= 64) {
        unsigned long long v = (lane < base) ? cand[lane] : ~0ull;
        unsigned hi = (unsigned)(v >> 32);
        unsigned hs = wave_bitonic_sort_u32(hi, lane);
        unsigned t2 = (unsigned)__shfl((int)hs, 19, 64);
        bool sel2 = (lane < base) && (hi <= t2);
        unsigned long long m2 = __ballot(sel2);
        if ((int)__popcll(m2) == KNN) {
            if (sel2) out[(int)__popcll(m2 & below)] = (int)(v & 0xffffffffu);
        } else {
            unsigned long long sv = wave_bitonic_sort(v, lane);
            if (lane < KNN) out[lane] = (int)(sv & 0xffffffffu);
        }
    } else {
        u64x16 k;
#pragma unroll
        for (int j = 0; j < 16; ++j)
            k[j] = ((unsigned long long)d[j] << 32) | (unsigned)(j * 64 + lane);
        topk20_wave(k, lane, out);
    }
}

// ---------------- weight-conversion helpers ----------------
static __device__ __forceinline__ void pack_store(unsigned short h[8],
                                                  unsigned short l[8], size_t ci,
                                                  unsigned short* __restrict__ Wh,
                                                  unsigned short* __restrict__ Wl) {
    uint4 hp, lp;
    hp.x = h[0] | ((unsigned)h[1] << 16);
    hp.y = h[2] | ((unsigned)h[3] << 16);
    hp.z = h[4] | ((unsigned)h[5] << 16);
    hp.w = h[6] | ((unsigned)h[7] << 16);
    lp.x = l[0] | ((unsigned)l[1] << 16);
    lp.y = l[2] | ((unsigned)l[3] << 16);
    lp.z = l[4] | ((unsigned)l[5] << 16);
    lp.w = l[6] | ((unsigned)l[7] << 16);
    ((uint4*)Wh)[ci] = hp;
    ((uint4*)Wl)[ci] = lp;
}

static __device__ void conv_edge_w(const float* __restrict__ W, int Cin, int Cout,
                                   int g, unsigned short* __restrict__ Wh,
                                   unsigned short* __restrict__ Wl) {
    int N2 = 2 * Cout;
    if (g >= (Cin / 8) * N2) return;
    int n = g % N2, ks = g / N2;
    unsigned short h[8], l[8];
#pragma unroll
    for (int j = 0; j < 8; ++j) {
        int c = ks * 8 + j;
        float v;
        if (n < Cout)
            v = W[(size_t)c * Cout + n] - W[(size_t)(Cin + c) * Cout + n];
        else
            v = W[(size_t)(Cin + c) * Cout + (n - Cout)];
        split_bf16(v, h[j], l[j]);
    }
    pack_store(h, l, (size_t)ks * N2 + n, Wh, Wl);
}

// ---------------- LDS overlays ----------------
struct Knn3Shared {
    float sx[3][1024];
    float ssq[1024];
    unsigned long long cand[4][64];
};
struct Edge1Shared {
    float sX[3][68];
    float sW[3][132];
};
union L1Shared {
    Knn3Shared k;
    Edge1Shared e;
};

struct KnnShared {
    float sD[16][1028];
    float sqa[16];
    float sqb[1024];
    unsigned long long cand[4][64];
};
struct EdgeShared {
    uint4 sAh[2][4][132];
    uint4 sAl[2][4][132];
    uint4 sBh[2][4][132];
    uint4 sBl[2][4][132];
};
union LayerShared {
    KnnShared k;
    EdgeShared e;
};

// ---------------- merged: knn3 (0-511) + f32 edge GEMM (512-639) + W-converts -------
__global__ __launch_bounds__(256) void knn3_edge_conv_kernel(
        const float* __restrict__ x, const float* __restrict__ W,
        const float* __restrict__ bias, int* __restrict__ idx, float* __restrict__ AB,
        const float* __restrict__ Wm, const float* __restrict__ W2,
        const float* __restrict__ W3, const float* __restrict__ W4,
        unsigned short* __restrict__ Wmh, unsigned short* __restrict__ Wml,
        unsigned short* __restrict__ W2h, unsigned short* __restrict__ W2l,
        unsigned short* __restrict__ W3h, unsigned short* __restrict__ W3l,
        unsigned short* __restrict__ W4h, unsigned short* __restrict__ W4l) {
    __shared__ L1Shared su;
    const int bid = blockIdx.x;
    const int tid = threadIdx.x;

    if (bid < 512) {
        // ---- kNN, 16 points per block ----
        Knn3Shared& S = su.k;
        const int wid = tid >> 6, lane = tid & 63;
        const int b = bid >> 6, p0 = (bid & 63) * 16;
        const int g0 = b * NP;
        const float* xb = x + (size_t)g0 * 3;

        for (int t = tid; t < 1024; t += 256) {
            float vx = xb[t * 3 + 0], vy = xb[t * 3 + 1], vz = xb[t * 3 + 2];
            S.sx[0][t] = vx;
            S.sx[1][t] = vy;
            S.sx[2][t] = vz;
            S.ssq[t] = vx * vx + vy * vy + vz * vz;  // ascending-c order
        }
        __syncthreads();

        for (int rr = 0; rr < 4; ++rr) {
            int pr = p0 + wid * 4 + rr;
            const float px = S.sx[0][pr], py = S.sx[1][pr], pz = S.sx[2][pr];
            const float sqp = S.ssq[pr];
            u32x16 d;
#pragma unroll
            for (int j = 0; j < 16; ++j) {
                int q = j * 64 + lane;
                float dot = px * S.sx[0][q];
                dot += py * S.sx[1][q];
                dot += pz * S.sx[2][q];
                float dv = sqp + S.ssq[q] - 2.0f * dot;
                unsigned u = __float_as_uint(dv);
                d[j] = (u & 0x80000000u) ? ~u : (u | 0x80000000u);
            }
            topk20_sel(d, lane, S.cand[wid], idx + (size_t)(g0 + pr) * KNN);
        }
    } else if (bid < 640) {
        // ---- f32 edge GEMM <3,64>: AB[p, 0:64]=x.(W1-W2)+b, [64:128]=x.W2 ----
        Edge1Shared& S = su.e;
        constexpr int Cin = 3, Cout = 64, N2 = 128;
        const int p0 = (bid - 512) * 64;
        const int tx = tid & 15, ty = tid >> 4;

        for (int t = tid; t < 64 * Cin; t += 256) {
            int m = t / Cin, c = t - m * Cin;
            S.sX[c][m] = x[(size_t)(p0 + m) * Cin + c];
        }
        for (int t = tid; t < Cin * 128; t += 256) {
            int c = t >> 7, n = t & 127;
            float w;
            if (n < Cout)
                w = W[(size_t)c * Cout + n] - W[(size_t)(Cin + c) * Cout + n];
            else
                w = W[(size_t)(Cin + c) * Cout + (n - Cout)];
            S.sW[c][n] = w;
        }
        __syncthreads();

        float acc[4][8];
#pragma unroll
        for (int i = 0; i < 4; ++i)
#pragma unroll
            for (int j = 0; j < 8; ++j) acc[i][j] = 0.f;

#pragma unroll
        for (int c = 0; c < Cin; ++c) {
            float4 a4 = *(const float4*)&S.sX[c][ty * 4];
            float4 w0 = *(const float4*)&S.sW[c][tx * 4];
            float4 w1 = *(const float4*)&S.sW[c][64 + tx * 4];
            float av[4] = {a4.x, a4.y, a4.z, a4.w};
#pragma unroll
            for (int i = 0; i < 4; ++i) {
                acc[i][0] += av[i] * w0.x;
                acc[i][1] += av[i] * w0.y;
                acc[i][2] += av[i] * w0.z;
                acc[i][3] += av[i] * w0.w;
                acc[i][4] += av[i] * w1.x;
                acc[i][5] += av[i] * w1.y;
                acc[i][6] += av[i] * w1.z;
                acc[i][7] += av[i] * w1.w;
            }
        }

        float4 bb0 = *(const float4*)&bias[tx * 4];
#pragma unroll
        for (int i = 0; i < 4; ++i) {
            float* orow = AB + (size_t)(p0 + ty * 4 + i) * N2;
            float4 o0, o1;
            o0.x = acc[i][0] + bb0.x;
            o0.y = acc[i][1] + bb0.y;
            o0.z = acc[i][2] + bb0.z;
            o0.w = acc[i][3] + bb0.w;
            o1.x = acc[i][4];
            o1.y = acc[i][5];
            o1.z = acc[i][6];
            o1.w = acc[i][7];
            *(float4*)&orow[tx * 4] = o0;
            *(float4*)&orow[64 + tx * 4] = o1;
        }
    } else {
        // ---- weight conversions (data-independent of pos) ----
        int cid = bid - 640;
        if (cid < 256) {
            int g = cid * 256 + tid;  // 65536 Wm jobs
            int n = g & 1023, ks = g >> 10;
            unsigned short h[8], l[8];
#pragma unroll
            for (int j = 0; j < 8; ++j) {
                float v = Wm[(size_t)(ks * 8 + j) * 1024 + n];
                split_bf16(v, h[j], l[j]);
            }
            pack_store(h, l, (size_t)ks * 1024 + n, Wmh, Wml);
        } else if (cid < 288) {
            conv_edge_w(W4, 128, 256, (cid - 256) * 256 + tid, W4h, W4l);
        } else if (cid < 296) {
            conv_edge_w(W3, 64, 128, (cid - 288) * 256 + tid, W3h, W3l);
        } else {
            conv_edge_w(W2, 64, 64, (cid - 296) * 256 + tid, W2h, W2l);
        }
    }
}

// ---------------- merged layer kernel: MFMA knn (blocks 0-511) + MFMA edge GEMM -----
template <int C, int Cout>
__global__ __launch_bounds__(256, 2) void layer_kernel(
        const unsigned short* __restrict__ Xhp, const unsigned short* __restrict__ Xlp,
        const float* __restrict__ sqn, int* __restrict__ idx,
        const unsigned short* __restrict__ Whp, const unsigned short* __restrict__ Wlp,
        const float* __restrict__ bias, float* __restrict__ AB) {
    __shared__ LayerShared su;
    constexpr int NCK = C / 32;
    const int bid = blockIdx.x;
    const int tid = threadIdx.x;
    const int wid = tid >> 6, lane = tid & 63;
    const int fkb = lane >> 4, flm = lane & 15;
    const uint4* Ah4 = (const uint4*)Xhp;
    const uint4* Al4 = (const uint4*)Xlp;

    if (bid < 512) {
        // ---- fused MFMA dist + top-20 ----
        KnnShared& S = su.k;
        const int b = bid >> 6, rg = bid & 63;
        const int g0 = b * NP;
        const int p0 = rg * 16;

        if (tid < 16) S.sqa[tid] = sqn[g0 + p0 + tid];
        for (int t = tid; t < 1024; t += 256) S.sqb[t] = sqn[g0 + t];
        __syncthreads();

        uint4 fAh[NCK], fAl[NCK];
#pragma unroll
        for (int kk = 0; kk < NCK; ++kk) {
            size_t a = (size_t)(4 * kk + fkb) * NPTS + g0 + p0 + flm;
            fAh[kk] = Ah4[a];
            fAl[kk] = Al4[a];
        }

        const int r4 = fkb * 4, cc = flm;

#pragma unroll
        for (int t = 0; t < 2; ++t) {
            const int c0 = (wid + t * 4) * 128;
            f32x4 acc[8];
#pragma unroll
            for (int j = 0; j < 8; ++j) acc[j] = {0.f, 0.f, 0.f, 0.f};

#pragma unroll
            for (int kk = 0; kk < NCK; ++kk) {
                uint4 fBh[8], fBl[8];
#pragma unroll
                for (int j = 0; j < 8; ++j) {
                    size_t bi = (size_t)(4 * kk + fkb) * NPTS + g0 + c0 + j * 16 + flm;
                    fBh[j] = Ah4[bi];
                    fBl[j] = Al4[bi];
                }
                bf16x8 ah = *(const bf16x8*)&fAh[kk];
                bf16x8 al = *(const bf16x8*)&fAl[kk];
#pragma unroll
                for (int j = 0; j < 8; ++j) {
                    bf16x8 bh = *(const bf16x8*)&fBh[j];
                    bf16x8 bl = *(const bf16x8*)&fBl[j];
                    acc[j] = __builtin_amdgcn_mfma_f32_16x16x32_bf16(ah, bh, acc[j], 0, 0, 0);
                    acc[j] = __builtin_amdgcn_mfma_f32_16x16x32_bf16(ah, bl, acc[j], 0, 0, 0);
                    acc[j] = __builtin_amdgcn_mfma_f32_16x16x32_bf16(al, bh, acc[j], 0, 0, 0);
                }
            }

#pragma unroll
            for (int r = 0; r < 4; ++r) {
                int row = r4 + r;
                float sp = S.sqa[row];
#pragma unroll
                for (int j = 0; j < 8; ++j) {
                    int col = c0 + j * 16 + cc;
                    S.sD[row][col] = sp + S.sqb[col] - 2.0f * acc[j][r];
                }
            }
        }
        __syncthreads();

        for (int rr = 0; rr < 4; ++rr) {
            int row = wid * 4 + rr;
            u32x16 d;
#pragma unroll
            for (int j = 0; j < 16; ++j) {
                int q = j * 64 + lane;
                unsigned u = __float_as_uint(S.sD[row][q]);
                d[j] = (u & 0x80000000u) ? ~u : (u | 0x80000000u);
            }
            topk20_sel(d, lane, S.cand[wid], idx + (size_t)(g0 + p0 + row) * KNN);
        }
    } else {
        // ---- MFMA split-bf16 edge GEMM ----
        EdgeShared& S = su.e;
        constexpr int N2 = 2 * Cout;
        constexpr int NX = N2 / 128;
        const int eb = bid - 512;
        const int n0 = (eb % NX) * 128;
        const int p0 = (eb / NX) * 128;
        const int wm = (wid >> 1) * 64, wn = (wid & 1) * 64;

        f32x4 acc[4][4];
#pragma unroll
        for (int i = 0; i < 4; ++i)
#pragma unroll
            for (int j = 0; j < 4; ++j) acc[i][j] = {0.f, 0.f, 0.f, 0.f};

        const uint4* Wh4 = (const uint4*)Whp;
        const uint4* Wl4 = (const uint4*)Wlp;

        const int m0 = tid & 127, kb0 = tid >> 7;
        uint4 rAh0, rAl0, rBh0, rBl0, rAh1, rAl1, rBh1, rBl1;

#define EM_LOAD(ck)                                                     \
    {                                                                   \
        int ksb = (ck) * 4;                                             \
        size_t a0 = (size_t)(ksb + kb0) * NPTS + p0 + m0;               \
        size_t a1 = (size_t)(ksb + kb0 + 2) * NPTS + p0 + m0;           \
        size_t b0 = (size_t)(ksb + kb0) * N2 + n0 + m0;                 \
        size_t b1 = (size_t)(ksb + kb0 + 2) * N2 + n0 + m0;             \
        rAh0 = Ah4[a0]; rAl0 = Al4[a0];                                 \
        rAh1 = Ah4[a1]; rAl1 = Al4[a1];                                 \
        rBh0 = Wh4[b0]; rBl0 = Wl4[b0];                                 \
        rBh1 = Wh4[b1]; rBl1 = Wl4[b1];                                 \
    }

#define EM_WRITE(buf)                                                         \
    {                                                                         \
        S.sAh[buf][kb0][m0] = rAh0;  S.sAl[buf][kb0][m0] = rAl0;              \
        S.sAh[buf][kb0 + 2][m0] = rAh1;  S.sAl[buf][kb0 + 2][m0] = rAl1;      \
        S.sBh[buf][kb0][m0] = rBh0;  S.sBl[buf][kb0][m0] = rBl0;              \
        S.sBh[buf][kb0 + 2][m0] = rBh1;  S.sBl[buf][kb0 + 2][m0] = rBl1;      \
    }

        EM_LOAD(0);
        EM_WRITE(0);
        __syncthreads();

        for (int ck = 0; ck < NCK; ++ck) {
            const int buf = ck & 1;
            if (ck < NCK - 1) EM_LOAD(ck + 1);

            bf16x8 fAh[4], fAl[4], fBh[4], fBl[4];
#pragma unroll
            for (int i = 0; i < 4; ++i) {
                fAh[i] = *(const bf16x8*)&S.sAh[buf][fkb][wm + i * 16 + flm];
                fAl[i] = *(const bf16x8*)&S.sAl[buf][fkb][wm + i * 16 + flm];
                fBh[i] = *(const bf16x8*)&S.sBh[buf][fkb][wn + i * 16 + flm];
                fBl[i] = *(const bf16x8*)&S.sBl[buf][fkb][wn + i * 16 + flm];
            }
#pragma unroll
            for (int i = 0; i < 4; ++i)
#pragma unroll
                for (int j = 0; j < 4; ++j) {
                    acc[i][j] = __builtin_amdgcn_mfma_f32_16x16x32_bf16(
                            fAh[i], fBh[j], acc[i][j], 0, 0, 0);
                    acc[i][j] = __builtin_amdgcn_mfma_f32_16x16x32_bf16(
                            fAh[i], fBl[j], acc[i][j], 0, 0, 0);
                    acc[i][j] = __builtin_amdgcn_mfma_f32_16x16x32_bf16(
                            fAl[i], fBh[j], acc[i][j], 0, 0, 0);
                }

            if (ck < NCK - 1) EM_WRITE(buf ^ 1);
            __syncthreads();
        }

        const int r4 = (lane >> 4) * 4, cc = lane & 15;
        float bj[4];
#pragma unroll
        for (int j = 0; j < 4; ++j) {
            int cg = n0 + wn + j * 16 + cc;
            bj[j] = (cg < Cout) ? bias[cg] : 0.f;
        }
#pragma unroll
        for (int i = 0; i < 4; ++i) {
#pragma unroll
            for (int r = 0; r < 4; ++r) {
                int row = wm + i * 16 + r4 + r;
                float* orow = AB + (size_t)(p0 + row) * N2 + n0;
#pragma unroll
                for (int j = 0; j < 4; ++j)
                    orow[wn + j * 16 + cc] = acc[i][j][r] + bj[j];
            }
        }
#undef EM_LOAD
#undef EM_WRITE
    }
}

// ---------------- gather-max + panel write + (optional) exact sqnorm ----------------
template <int Cout, bool WSQ>
__global__ __launch_bounds__(256) void gather_max_panel_kernel(
        const float* __restrict__ AB, const int* __restrict__ idx,
        float* __restrict__ y, unsigned short* __restrict__ Xh,
        unsigned short* __restrict__ Xl, float* __restrict__ sqn) {
    constexpr int N2 = 2 * Cout;
    constexpr int TPP = Cout / 4;
    constexpr int PPB = 256 / TPP;
    constexpr int RS = N2 / 4;
    const int pp = threadIdx.x / TPP;
    const int t = threadIdx.x % TPP;
    const int p = blockIdx.x * PPB + pp;
    const int base = p & ~(NP - 1);

    __shared__ int s_idx[PPB][KNN];
    __shared__ float srow[PPB][Cout];
    for (int tt = threadIdx.x; tt < PPB * KNN; tt += 256) {
        int a = tt / KNN, r = tt - a * KNN;
        s_idx[a][r] = idx[(size_t)(blockIdx.x * PPB + a) * KNN + r];
    }
    __syncthreads();

    const float4* Brow = (const float4*)(AB + (size_t)base * N2 + Cout);

    int q0 = s_idx[pp][0];
    float4 m = Brow[(size_t)q0 * RS + t];
#pragma unroll
    for (int j = 1; j < KNN; ++j) {
        int q = s_idx[pp][j];
        float4 v = Brow[(size_t)q * RS + t];
        m.x = fmaxf(m.x, v.x);
        m.y = fmaxf(m.y, v.y);
        m.z = fmaxf(m.z, v.z);
        m.w = fmaxf(m.w, v.w);
    }
    float4 a = *(const float4*)(AB + (size_t)p * N2 + 4 * t);
    float4 o;
    o.x = a.x + m.x;
    o.y = a.y + m.y;
    o.z = a.z + m.z;
    o.w = a.w + m.w;
    *(float4*)(y + (size_t)p * Cout + 4 * t) = o;

    // fused panel write: channels 4t..4t+3 -> ks = t>>1, half (t&1)
    unsigned short h[4], l[4];
    split_bf16(o.x, h[0], l[0]);
    split_bf16(o.y, h[1], l[1]);
    split_bf16(o.z, h[2], l[2]);
    split_bf16(o.w, h[3], l[3]);
    const int ks = t >> 1;
    size_t u2 = ((size_t)ks * NPTS + p) * 2 + (t & 1);
    uint2 hp, lp;
    hp.x = h[0] | ((unsigned)h[1] << 16);
    hp.y = h[2] | ((unsigned)h[3] << 16);
    lp.x = l[0] | ((unsigned)l[1] << 16);
    lp.y = l[2] | ((unsigned)l[3] << 16);
    ((uint2*)Xh)[u2] = hp;
    ((uint2*)Xl)[u2] = lp;

    if constexpr (WSQ) {
        // exact sqnorm: same ascending-c serial sum as the old sqnorm_kernel
        *(float4*)&srow[pp][4 * t] = o;
        __syncthreads();
        if (t == 0) {
            float s = 0.f;
            for (int c = 0; c < Cout; ++c) {
                float v = srow[pp][c];
                s += v * v;
            }
            sqn[p] = s;
        }
    }
}

// ---------------- catmean[b][512] = mean over p of cat ----------------
__global__ __launch_bounds__(256) void catmean_kernel(
        const float* __restrict__ x1, const float* __restrict__ x2,
        const float* __restrict__ x3, const float* __restrict__ x4,
        float* __restrict__ catmean) {
    const int n0 = blockIdx.x * 128;
    const int b = blockIdx.y;
    const int tid = threadIdx.x;
    const int col = n0 + (tid & 127);
    const int half = tid >> 7;
    __shared__ float sred[256];

    const float* src;
    int cw, coff;
    if (col < 64) { src = x1; cw = 64; coff = col; }
    else if (col < 128) { src = x2; cw = 64; coff = col - 64; }
    else if (col < 256) { src = x3; cw = 128; coff = col - 128; }
    else { src = x4; cw = 256; coff = col - 256; }

    float s = 0.f;
    const float* base = src + ((size_t)b * NP + half * 512) * cw + coff;
    for (int p = 0; p < 512; ++p) s += base[(size_t)p * cw];
    sred[tid] = s;
    __syncthreads();
    if (tid < 128)
        catmean[(size_t)b * 512 + col] = (sred[tid] + sred[tid + 128]) * (1.0f / 1024.0f);
}

// ---------------- gmeanv[b][1024] = catmean . Wm + bm ----------------
__global__ __launch_bounds__(256) void gmean_kernel(const float* __restrict__ catmean,
                                                    const float* __restrict__ Wm,
                                                    const float* __restrict__ bm,
                                                    float* __restrict__ gmeanv) {
    const int n0 = blockIdx.x * 128;
    const int b = blockIdx.y;
    const int tid = threadIdx.x;
    const int cg = tid & 31, kp = tid >> 5;
    const int col = n0 + cg * 4;
    __shared__ float4 part[8][32];

    float4 acc = {0.f, 0.f, 0.f, 0.f};
    for (int k = kp * 64; k < kp * 64 + 64; ++k) {
        float g = catmean[(size_t)b * 512 + k];
        float4 w = *(const float4*)&Wm[(size_t)k * 1024 + col];
        acc.x += g * w.x;
        acc.y += g * w.y;
        acc.z += g * w.z;
        acc.w += g * w.w;
    }
    part[kp][cg] = acc;
    __syncthreads();
    if (tid < 32) {
        float4 s = part[0][tid];
#pragma unroll
        for (int z = 1; z < 8; ++z) {
            float4 p = part[z][tid];
            s.x += p.x; s.y += p.y; s.z += p.z; s.w += p.w;
        }
        float4 bb = *(const float4*)&bm[n0 + tid * 4];
        s.x += bb.x; s.y += bb.y; s.z += bb.z; s.w += bb.w;
        *(float4*)&gmeanv[(size_t)b * 1024 + n0 + tid * 4] = s;
    }
}

// ---------------- MFMA split-bf16 cat-GEMM + max pool ----------------
__global__ __launch_bounds__(256, 2) void gemm_cat_pool_kernel(
        const unsigned short* __restrict__ Ahp, const unsigned short* __restrict__ Alp,
        const unsigned short* __restrict__ Whp, const unsigned short* __restrict__ Wlp,
        float* __restrict__ pmax) {
    const int bid = blockIdx.x;  // 512
    const int xcd = bid & 7, pos = bid >> 3;
    const int nb = pos & 7, pb = (xcd << 3) | (pos >> 3);
    const int n0 = nb * 128, p0 = pb * 128;
    const int tid = threadIdx.x;
    const int wid = tid >> 6, lane = tid & 63;
    const int wm = (wid >> 1) * 64, wn = (wid & 1) * 64;

    __shared__ uint4 sAh[2][4][132], sAl[2][4][132], sBh[2][4][132], sBl[2][4][132];
    __shared__ float sMax[2][128];

    f32x4 acc[4][4];
#pragma unroll
    for (int i = 0; i < 4; ++i)
#pragma unroll
        for (int j = 0; j < 4; ++j) acc[i][j] = {0.f, 0.f, 0.f, 0.f};

    const uint4* Ah4 = (const uint4*)Ahp;
    const uint4* Al4 = (const uint4*)Alp;
    const uint4* Wh4 = (const uint4*)Whp;
    const uint4* Wl4 = (const uint4*)Wlp;

    const int m0 = tid & 127, kb0 = tid >> 7;
    uint4 rAh0, rAl0, rBh0, rBl0, rAh1, rAl1, rBh1, rBl1;

#define MP_LOAD(ck)                                                     \
    {                                                                   \
        int ksb = (ck) * 4;                                             \
        size_t a0 = (size_t)(ksb + kb0) * 8192 + p0 + m0;               \
        size_t a1 = (size_t)(ksb + kb0 + 2) * 8192 + p0 + m0;           \
        size_t b0 = (size_t)(ksb + kb0) * 1024 + n0 + m0;               \
        size_t b1 = (size_t)(ksb + kb0 + 2) * 1024 + n0 + m0;           \
        rAh0 = Ah4[a0]; rAl0 = Al4[a0];                                 \
        rAh1 = Ah4[a1]; rAl1 = Al4[a1];                                 \
        rBh0 = Wh4[b0]; rBl0 = Wl4[b0];                                 \
        rBh1 = Wh4[b1]; rBl1 = Wl4[b1];                                 \
    }

#define MP_WRITE(buf)                                                   \
    {                                                                   \
        sAh[buf][kb0][m0] = rAh0;  sAl[buf][kb0][m0] = rAl0;            \
        sAh[buf][kb0 + 2][m0] = rAh1;  sAl[buf][kb0 + 2][m0] = rAl1;    \
        sBh[buf][kb0][m0] = rBh0;  sBl[buf][kb0][m0] = rBl0;            \
        sBh[buf][kb0 + 2][m0] = rBh1;  sBl[buf][kb0 + 2][m0] = rBl1;    \
    }

    MP_LOAD(0);
    MP_WRITE(0);
    __syncthreads();

    const int fkb = lane >> 4, flm = lane & 15;

    for (int ck = 0; ck < 16; ++ck) {
        const int buf = ck & 1;
        if (ck < 15) MP_LOAD(ck + 1);

        bf16x8 fAh[4], fAl[4], fBh[4], fBl[4];
#pragma unroll
        for (int i = 0; i < 4; ++i) {
            fAh[i] = *(const bf16x8*)&sAh[buf][fkb][wm + i * 16 + flm];
            fAl[i] = *(const bf16x8*)&sAl[buf][fkb][wm + i * 16 + flm];
            fBh[i] = *(const bf16x8*)&sBh[buf][fkb][wn + i * 16 + flm];
            fBl[i] = *(const bf16x8*)&sBl[buf][fkb][wn + i * 16 + flm];
        }
#pragma unroll
        for (int i = 0; i < 4; ++i)
#pragma unroll
            for (int j = 0; j < 4; ++j) {
                acc[i][j] = __builtin_amdgcn_mfma_f32_16x16x32_bf16(fAh[i], fBh[j],
                                                                    acc[i][j], 0, 0, 0);
                acc[i][j] = __builtin_amdgcn_mfma_f32_16x16x32_bf16(fAh[i], fBl[j],
                                                                    acc[i][j], 0, 0, 0);
                acc[i][j] = __builtin_amdgcn_mfma_f32_16x16x32_bf16(fAl[i], fBh[j],
                                                                    acc[i][j], 0, 0, 0);
            }

        if (ck < 15) MP_WRITE(buf ^ 1);
        __syncthreads();
    }

    float cm[4];
#pragma unroll
    for (int j = 0; j < 4; ++j) {
        float m = acc[0][j][0];
#pragma unroll
        for (int i = 0; i < 4; ++i)
#pragma unroll
            for (int r = 0; r < 4; ++r) m = fmaxf(m, acc[i][j][r]);
        m = fmaxf(m, __shfl_xor(m, 16, 64));
        m = fmaxf(m, __shfl_xor(m, 32, 64));
        cm[j] = m;
    }
    if (lane < 16) {
#pragma unroll
        for (int j = 0; j < 4; ++j) sMax[wid >> 1][wn + j * 16 + lane] = cm[j];
    }
    __syncthreads();
    if (tid < 128)
        pmax[(size_t)pb * 1024 + n0 + tid] = fmaxf(sMax[0][tid], sMax[1][tid]);
#undef MP_LOAD
#undef MP_WRITE
}

// ---------------- fc_a ----------------
__global__ __launch_bounds__(256) void fc_a_kernel(const float* __restrict__ pmax,
                                                   const float* __restrict__ gmeanv,
                                                   const float* __restrict__ bm,
                                                   const float* __restrict__ Wa,
                                                   const float* __restrict__ ba,
                                                   float* __restrict__ ha) {
    const int b = blockIdx.y;
    const int n0 = blockIdx.x * 64;
    const int tid = threadIdx.x;
    __shared__ float gm[2048];
    __shared__ float4 part[16][16];

    for (int c = tid; c < 1024; c += 256) {
        float m = pmax[(size_t)(b * 8) * 1024 + c];
#pragma unroll
        for (int z = 1; z < 8; ++z) m = fmaxf(m, pmax[(size_t)(b * 8 + z) * 1024 + c]);
        gm[c] = m + bm[c];
        gm[1024 + c] = gmeanv[(size_t)b * 1024 + c];
    }
    __syncthreads();

    const int cg = tid & 15, kp = tid >> 4;
    const int co = n0 + cg * 4;
    float4 acc = {0.f, 0.f, 0.f, 0.f};
    const float* Wp = Wa + (size_t)(kp * 128) * 512 + co;
    const float* gp = gm + kp * 128;
#pragma unroll 8
    for (int k = 0; k < 128; ++k) {
        float g = gp[k];
        float4 w = *(const float4*)&Wp[(size_t)k * 512];
        acc.x += g * w.x;
        acc.y += g * w.y;
        acc.z += g * w.z;
        acc.w += g * w.w;
    }
    part[kp][cg] = acc;
    __syncthreads();
    if (tid < 16) {
        float4 s = part[0][tid];
#pragma unroll
        for (int z = 1; z < 16; ++z) {
            float4 p = part[z][tid];
            s.x += p.x; s.y += p.y; s.z += p.z; s.w += p.w;
        }
        float4 bb = *(const float4*)&ba[n0 + tid * 4];
        s.x += bb.x; s.y += bb.y; s.z += bb.z; s.w += bb.w;
        *(float4*)&ha[(size_t)b * 512 + n0 + tid * 4] = s;
    }
}

// ---------------- fc_b with fused batchnorm+leaky on input ----------------
__global__ __launch_bounds__(256) void fc_b_bn_kernel(const float* __restrict__ ha,
                                                      const float* __restrict__ g,
                                                      const float* __restrict__ be,
                                                      const float* __restrict__ Wb,
                                                      const float* __restrict__ bb,
                                                      float* __restrict__ hb) {
    const int b = blockIdx.y;
    const int n0 = blockIdx.x * 64;
    const int tid = threadIdx.x;
    __shared__ float shall[NB][512];
    __shared__ float sh[512];
    __shared__ float4 part[16][16];

    for (int t = tid; t < NB * 512; t += 256) shall[t >> 9][t & 511] = ha[t];
    __syncthreads();

    for (int c = tid; c < 512; c += 256) {
        float mu = 0.f;
        for (int z = 0; z < NB; ++z) mu += shall[z][c];
        mu *= 0.125f;
        float var = 0.f;
        for (int z = 0; z < NB; ++z) {
            float d = shall[z][c] - mu;
            var += d * d;
        }
        var *= 0.125f;
        float inv = 1.0f / sqrtf(var + 1e-5f);
        float v = (shall[b][c] - mu) * inv * g[c] + be[c];
        sh[c] = v >= 0.f ? v : 0.2f * v;
    }
    __syncthreads();

    const int cg = tid & 15, kp = tid >> 4;
    const int co = n0 + cg * 4;
    float4 acc = {0.f, 0.f, 0.f, 0.f};
#pragma unroll 8
    for (int k = 0; k < 32; ++k) {
        float gg = sh[kp * 32 + k];
        float4 w = *(const float4*)&Wb[(size_t)(kp * 32 + k) * 256 + co];
        acc.x += gg * w.x;
        acc.y += gg * w.y;
        acc.z += gg * w.z;
        acc.w += gg * w.w;
    }
    part[kp][cg] = acc;
    __syncthreads();
    if (tid < 16) {
        float4 s = part[0][tid];
#pragma unroll
        for (int z = 1; z < 16; ++z) {
            float4 p = part[z][tid];
            s.x += p.x; s.y += p.y; s.z += p.z; s.w += p.w;
        }
        float4 bv = *(const float4*)&bb[n0 + tid * 4];
        s.x += bv.x; s.y += bv.y; s.z += bv.z; s.w += bv.w;
        *(float4*)&hb[(size_t)b * 256 + n0 + tid * 4] = s;
    }
}

// ---------------- fc_c with fused batchnorm+leaky on input ----------------
__global__ __launch_bounds__(256) void fc_c_bn_kernel(const float* __restrict__ hbin,
                                                      const float* __restrict__ g,
                                                      const float* __restrict__ be,
                                                      const float* __restrict__ Wc,
                                                      const float* __restrict__ bc,
                                                      float* __restrict__ outp) {
    const int tid = threadIdx.x;
    __shared__ float shn[NB][256];

    {
        int c = tid;  // 256 threads <-> 256 cols
        float col[NB];
#pragma unroll
        for (int z = 0; z < NB; ++z) col[z] = hbin[z * 256 + c];
        float mu = 0.f;
#pragma unroll
        for (int z = 0; z < NB; ++z) mu += col[z];
        mu *= 0.125f;
        float var = 0.f;
#pragma unroll
        for (int z = 0; z < NB; ++z) {
            float d = col[z] - mu;
            var += d * d;
        }
        var *= 0.125f;
        float inv = 1.0f / sqrtf(var + 1e-5f);
#pragma unroll
        for (int z = 0; z < NB; ++z) {
            float v = (col[z] - mu) * inv * g[c] + be[c];
            shn[z][c] = v >= 0.f ? v : 0.2f * v;
        }
    }
    __syncthreads();

    int t = blockIdx.x * 256 + tid;  // 8*40 outputs
    if (t < 8 * 40) {
        int b = t / 40, o = t - b * 40;
        float s = bc[o];
        for (int c = 0; c < 256; ++c) s += shn[b][c] * Wc[c * 40 + o];
        outp[t] = s;
    }
}

extern "C" void kernel_launch(void* const* d_in, const int* in_sizes, int n_in,
                              void* d_out, int out_size, void* d_ws, size_t ws_size,
                              hipStream_t stream) {
    const float* pos = (const float*)d_in[0];
    const float* W1 = (const float*)d_in[2];
    const float* b1 = (const float*)d_in[3];
    const float* W2 = (const float*)d_in[4];
    const float* b2 = (const float*)d_in[5];
    const float* W3 = (const float*)d_in[6];
    const float* b3 = (const float*)d_in[7];
    const float* W4 = (const float*)d_in[8];
    const float* b4 = (const float*)d_in[9];
    const float* Wm = (const float*)d_in[10];
    const float* bm = (const float*)d_in[11];
    const float* Wa = (const float*)d_in[12];
    const float* ba = (const float*)d_in[13];
    const float* ga = (const float*)d_in[14];
    const float* bea = (const float*)d_in[15];
    const float* Wb = (const float*)d_in[16];
    const float* bb = (const float*)d_in[17];
    const float* gb = (const float*)d_in[18];
    const float* beb = (const float*)d_in[19];
    const float* Wc = (const float*)d_in[20];
    const float* bc = (const float*)d_in[21];
    float* out = (float*)d_out;

    char* ws = (char*)d_ws;
    size_t off = 0;
    auto alloc = [&](size_t bytes) {
        void* p = ws + off;
        off += (bytes + 255) & ~(size_t)255;
        return p;
    };
    int* idx = (int*)alloc((size_t)NPTS * KNN * 4);
    float* x1 = (float*)alloc((size_t)NPTS * 64 * 4);
    float* x2 = (float*)alloc((size_t)NPTS * 64 * 4);
    float* x3 = (float*)alloc((size_t)NPTS * 128 * 4);
    float* x4 = (float*)alloc((size_t)NPTS * 256 * 4);
    float* scratch = (float*)alloc((size_t)NPTS * 512 * 4);  // AB (max 8192x512)
    float* pmax = (float*)alloc((size_t)64 * 1024 * 4);
    float* catmean = (float*)alloc(NB * 512 * 4);
    float* gmeanv = (float*)alloc(NB * 1024 * 4);
    float* ha = (float*)alloc(NB * 512 * 4);
    float* hb = (float*)alloc(NB * 256 * 4);
    float* sqn = (float*)alloc(NPTS * 4);
    // unified cat panels [64][8192][8]: x1 ks0-7, x2 ks8-15, x3 ks16-31, x4 ks32-63
    unsigned short* Ach = (unsigned short*)alloc((size_t)64 * NPTS * 8 * 2);
    unsigned short* Acl = (unsigned short*)alloc((size_t)64 * NPTS * 8 * 2);
    unsigned short* Wth = (unsigned short*)alloc((size_t)64 * 1024 * 8 * 2);
    unsigned short* Wtl = (unsigned short*)alloc((size_t)64 * 1024 * 8 * 2);
    unsigned short* W2h = (unsigned short*)alloc((size_t)8 * 128 * 8 * 2);
    unsigned short* W2l = (unsigned short*)alloc((size_t)8 * 128 * 8 * 2);
    unsigned short* W3h = (unsigned short*)alloc((size_t)8 * 256 * 8 * 2);
    unsigned short* W3l = (unsigned short*)alloc((size_t)8 * 256 * 8 * 2);
    unsigned short* W4h = (unsigned short*)alloc((size_t)16 * 512 * 8 * 2);
    unsigned short* W4l = (unsigned short*)alloc((size_t)16 * 512 * 8 * 2);
    (void)ws_size;

    float* AB = scratch;
    const size_t REG = (size_t)NPTS * 8;  // ushorts per ks-chunk
    unsigned short* x1h = Ach, *x1l = Acl;
    unsigned short* x2h = Ach + 8 * REG, *x2l = Acl + 8 * REG;
    unsigned short* x3h = Ach + 16 * REG, *x3l = Acl + 16 * REG;
    unsigned short* x4h = Ach + 32 * REG, *x4l = Acl + 32 * REG;

    // layer 1: kNN + f32 edge GEMM + ALL weight conversions (one launch, 940 blocks)
    knn3_edge_conv_kernel<<<940, 256, 0, stream>>>(pos, W1, b1, idx, AB, Wm, W2, W3,
                                                   W4, Wth, Wtl, W2h, W2l, W3h, W3l,
                                                   W4h, W4l);
    gather_max_panel_kernel<64, true><<<NPTS / 16, 256, 0, stream>>>(AB, idx, x1, x1h,
                                                                     x1l, sqn);

    // layer 2: merged MFMA knn + edge GEMM, then gather (+sqn of x2)
    layer_kernel<64, 64><<<512 + 64, 256, 0, stream>>>(x1h, x1l, sqn, idx, W2h, W2l,
                                                       b2, AB);
    gather_max_panel_kernel<64, true><<<NPTS / 16, 256, 0, stream>>>(AB, idx, x2, x2h,
                                                                     x2l, sqn);

    // layer 3
    layer_kernel<64, 128><<<512 + 128, 256, 0, stream>>>(x2h, x2l, sqn, idx, W3h, W3l,
                                                         b3, AB);
    gather_max_panel_kernel<128, true><<<NPTS / 8, 256, 0, stream>>>(AB, idx, x3, x3h,
                                                                     x3l, sqn);

    // layer 4 (no sqn needed for x4)
    layer_kernel<128, 256><<<512 + 256, 256, 0, stream>>>(x3h, x3l, sqn, idx, W4h, W4l,
                                                          b4, AB);
    gather_max_panel_kernel<256, false><<<NPTS / 4, 256, 0, stream>>>(AB, idx, x4, x4h,
                                                                      x4l, nullptr);

    // mean path (commutes with linear map)
    catmean_kernel<<<dim3(4, NB), 256, 0, stream>>>(x1, x2, x3, x4, catmean);
    gmean_kernel<<<dim3(8, NB), 256, 0, stream>>>(catmean, Wm, bm, gmeanv);

    // MFMA cat-GEMM + max pool (bias deferred to fc_a)
    gemm_cat_pool_kernel<<<512, 256, 0, stream>>>(Ach, Acl, Wth, Wtl, pmax);

    // head
    fc_a_kernel<<<dim3(8, NB), 256, 0, stream>>>(pmax, gmeanv, bm, Wa, ba, ha);
    fc_b_bn_kernel<<<dim3(4, NB), 256, 0, stream>>>(ha, ga, bea, Wb, bb, hb);
    fc_c_bn_kernel<<<2, 256, 0, stream>>>(hb, gb, beb, Wc, bc, out);
}